// Round 2
// baseline (433.696 us; speedup 1.0000x reference)
//
#include <hip/hip_runtime.h>
#include <hip/hip_bf16.h>
#include <math.h>

#define N_AC  8192
#define N_BC  8192
#define T_K   52
#define T_PAD 64

#define KSPLIT 4
#define KSEG   (N_BC / KSPLIT)   // 2048 per WG
#define BK     512               // k-chunk staged in LDS
#define NCHUNK (KSEG / BK)       // 4
#define LDS_STRIDE 520           // 512 + 8 bf16 pad -> 2-way bank alias (free)

typedef __bf16 bf16x8 __attribute__((ext_vector_type(8)));
typedef __bf16 bf16x4 __attribute__((ext_vector_type(4)));
typedef float  f32x4  __attribute__((ext_vector_type(4)));

// ---------------------------------------------------------------------------
// Prep: x (N_BC, T_K) fp32 -> xT (T_PAD, N_BC) bf16, zero-padded t in [52,64)
// ---------------------------------------------------------------------------
__global__ void xpose_kernel(const float* __restrict__ x, __bf16* __restrict__ xT) {
    int b = blockIdx.x * blockDim.x + threadIdx.x;
    if (b >= N_BC) return;
    #pragma unroll
    for (int t = 0; t < T_PAD; ++t) {
        float v = (t < T_K) ? x[b * T_K + t] : 0.0f;
        xT[(size_t)t * N_BC + b] = (__bf16)v;
    }
}

// ---------------------------------------------------------------------------
// Main: grid (512, KSPLIT). WG = 256 thr = 4 waves, owns 16 AC rows and a
// 2048-wide K segment. Per 512-k chunk: coalesced fp32 W loads -> bf16 ->
// padded LDS; each wave MFMAs its 128-k sub-range x 4 t-tiles. Epilogue
// applies the temporal kernel weighting and writes a per-kpart partial sum.
//
// Fragment layouts (verified round 1):
//   A: lane holds A[m = lane&15][k = (lane>>4)*8 + j]
//   B: lane holds B[k = (lane>>4)*8 + j][n = lane&15]
//   D: lane holds D[row = (lane>>4)*4 + r][col = lane&15]
// ---------------------------------------------------------------------------
__global__ __launch_bounds__(256) void ac_gemm_kernel(
    const float*  __restrict__ W,      // (N_AC, N_BC) fp32
    const __bf16* __restrict__ xT,     // (T_PAD, N_BC) bf16
    const float*  __restrict__ kern,   // (N_AC, T_K) fp32
    float*        __restrict__ partials) // (KSPLIT, N_AC)
{
    const int tid  = threadIdx.x;
    const int lane = tid & 63;
    const int wave = tid >> 6;
    const int quad = lane >> 4;
    const int l15  = lane & 15;
    const int a0   = blockIdx.x * 16;
    const int kbase = blockIdx.y * KSEG;

    __shared__ __bf16 As[16 * LDS_STRIDE];   // ~16.3 KB

    f32x4 acc[4] = {};   // 4 t-tiles: [0,16),[16,32),[32,48),[48,64)

    const int koff = quad * 8;
    const int ks   = wave * (BK / 4);        // this wave's 128-k sub-range

    for (int c = 0; c < NCHUNK; ++c) {
        const int kc = kbase + c * BK;

        // ---- stage 16 x BK fp32 -> bf16 LDS, lane-contiguous loads ----
        #pragma unroll
        for (int j = 0; j < 8; ++j) {
            int idx4 = j * 256 + tid;            // float4 index in 16x512 tile
            int row  = idx4 >> 7;                // 128 float4 per row
            int col  = (idx4 & 127) << 2;        // float column
            float4 f = *(const float4*)(W + (size_t)(a0 + row) * N_BC + kc + col);
            bf16x4 h;
            h[0] = (__bf16)f.x; h[1] = (__bf16)f.y;
            h[2] = (__bf16)f.z; h[3] = (__bf16)f.w;
            *(bf16x4*)&As[row * LDS_STRIDE + col] = h;
        }
        __syncthreads();

        // ---- compute: 4 k-steps x 4 t-tiles ----
        #pragma unroll
        for (int s = 0; s < 4; ++s) {
            int kk = ks + s * 32 + koff;
            bf16x8 af = *(const bf16x8*)&As[l15 * LDS_STRIDE + kk];
            #pragma unroll
            for (int nt = 0; nt < 4; ++nt) {
                bf16x8 bf = *(const bf16x8*)(xT + (size_t)(nt * 16 + l15) * N_BC + kc + kk);
                acc[nt] = __builtin_amdgcn_mfma_f32_16x16x32_bf16(af, bf, acc[nt], 0, 0, 0);
            }
        }
        __syncthreads();
    }

    // ---- temporal weighting: p[r] = sum_t kern[row, t] * y[row, t] ----
    float p[4] = {0.f, 0.f, 0.f, 0.f};
    #pragma unroll
    for (int nt = 0; nt < 4; ++nt) {
        int t = nt * 16 + l15;
        if (t < T_K) {
            #pragma unroll
            for (int r = 0; r < 4; ++r) {
                int grow = a0 + quad * 4 + r;
                p[r] += acc[nt][r] * kern[grow * T_K + t];
            }
        }
    }
    #pragma unroll
    for (int m = 1; m <= 8; m <<= 1) {
        #pragma unroll
        for (int r = 0; r < 4; ++r) p[r] += __shfl_xor(p[r], m);
    }

    __shared__ float red[4][16];
    if (l15 == 0) {
        #pragma unroll
        for (int r = 0; r < 4; ++r) red[wave][quad * 4 + r] = p[r];
    }
    __syncthreads();

    if (tid < 16) {
        float s = red[0][tid] + red[1][tid] + red[2][tid] + red[3][tid];
        partials[blockIdx.y * N_AC + a0 + tid] = s;
    }
}

// ---------------------------------------------------------------------------
// Final: reduce K-split partials, fused sigmoid
// ---------------------------------------------------------------------------
__global__ void ac_final_kernel(const float* __restrict__ partials,
                                const float* __restrict__ slope,
                                const float* __restrict__ offs,
                                float* __restrict__ out) {
    int a = blockIdx.x * blockDim.x + threadIdx.x;
    if (a >= N_AC) return;
    float s = partials[a] + partials[N_AC + a]
            + partials[2 * N_AC + a] + partials[3 * N_AC + a];
    float z = slope[a] * (s - offs[a]);
    out[a] = 1.0f / (1.0f + __expf(-z));
}

extern "C" void kernel_launch(void* const* d_in, const int* in_sizes, int n_in,
                              void* d_out, int out_size, void* d_ws, size_t ws_size,
                              hipStream_t stream) {
    const float* x     = (const float*)d_in[0];  // (N_BC, T_K)
    const float* W     = (const float*)d_in[1];  // (N_AC, N_BC)
    const float* kern  = (const float*)d_in[2];  // (N_AC, T_K)
    const float* slope = (const float*)d_in[3];  // (N_AC,)
    const float* offs  = (const float*)d_in[4];  // (N_AC,)
    float* out = (float*)d_out;

    __bf16* xT      = (__bf16*)d_ws;                              // 1 MB
    float* partials = (float*)((char*)d_ws + (size_t)T_PAD * N_BC * sizeof(__bf16));

    xpose_kernel<<<dim3(N_BC / 256), dim3(256), 0, stream>>>(x, xT);
    ac_gemm_kernel<<<dim3(N_AC / 16, KSPLIT), dim3(256), 0, stream>>>(
        W, xT, kern, partials);
    ac_final_kernel<<<dim3(N_AC / 256), dim3(256), 0, stream>>>(
        partials, slope, offs, out);
}

// Round 3
// 410.327 us; speedup vs baseline: 1.0570x; 1.0570x over previous
//
#include <hip/hip_runtime.h>
#include <hip/hip_bf16.h>
#include <math.h>

#define N_AC  8192
#define N_BC  8192
#define T_K   52
#define T_PAD 64

#define KSPLIT 16                 // total K-way split (per-wave segments)
#define KSEG   (N_BC / KSPLIT)    // 512 k per wave

typedef __bf16 bf16x8 __attribute__((ext_vector_type(8)));
typedef float  f32x4  __attribute__((ext_vector_type(4)));

// ---------------------------------------------------------------------------
// Prep: x (N_BC, T_K) fp32 -> xT (T_PAD, N_BC) bf16, zero-padded t in [52,64).
// Thread-per-element: gt = t*N_BC + b, consecutive tid -> consecutive b ->
// fully coalesced 2B stores. Reads bounce through L2 (x is 1.7 MB).
// ---------------------------------------------------------------------------
__global__ void xpose_kernel(const float* __restrict__ x, __bf16* __restrict__ xT) {
    int gt = blockIdx.x * blockDim.x + threadIdx.x;   // 0 .. T_PAD*N_BC-1
    int b = gt & (N_BC - 1);
    int t = gt >> 13;                                  // N_BC = 2^13
    float v = (t < T_K) ? x[b * T_K + t] : 0.0f;
    xT[gt] = (__bf16)v;
}

// ---------------------------------------------------------------------------
// GEMM: grid (512, 4) x 256 thr. NO LDS, NO barriers. Each wave independently
// owns 16 AC rows x a 512-wide K segment (16-way K split overall).
// A-fragments load directly from W (fp32 -> bf16 in-register); B-fragments
// from L2-resident xT. Epilogue: temporal kernel weighting + shuffle reduce,
// per-ksplit partial written to d_ws.
//
// Fragment layouts (verified rounds 1-2):
//   A: lane holds A[m = lane&15][k = (lane>>4)*8 + j]
//   B: lane holds B[k = (lane>>4)*8 + j][n = lane&15]
//   D: lane holds D[row = (lane>>4)*4 + r][col = lane&15]
// ---------------------------------------------------------------------------
__global__ __launch_bounds__(256) void ac_gemm_kernel(
    const float*  __restrict__ W,        // (N_AC, N_BC) fp32
    const __bf16* __restrict__ xT,       // (T_PAD, N_BC) bf16
    const float*  __restrict__ kern,     // (N_AC, T_K) fp32
    float*        __restrict__ partials) // (KSPLIT, N_AC)
{
    const int tid  = threadIdx.x;
    const int lane = tid & 63;
    const int wave = tid >> 6;
    const int quad = lane >> 4;
    const int l15  = lane & 15;
    const int a0   = blockIdx.x * 16;
    const int ksub = blockIdx.y * 4 + wave;     // 0..15
    const int kbeg = ksub * KSEG;

    const float* wrow = W + (size_t)(a0 + l15) * N_BC;
    const int koff = quad * 8;

    f32x4 acc[4] = {};   // 4 t-tiles: [0,16),[16,32),[32,48),[48,64)

    #pragma unroll 2
    for (int k = kbeg; k < kbeg + KSEG; k += 32) {
        const float* wp = wrow + k + koff;
        float4 w0 = *(const float4*)(wp);
        float4 w1 = *(const float4*)(wp + 4);
        bf16x8 af;
        af[0] = (__bf16)w0.x; af[1] = (__bf16)w0.y;
        af[2] = (__bf16)w0.z; af[3] = (__bf16)w0.w;
        af[4] = (__bf16)w1.x; af[5] = (__bf16)w1.y;
        af[6] = (__bf16)w1.z; af[7] = (__bf16)w1.w;
        #pragma unroll
        for (int nt = 0; nt < 4; ++nt) {
            bf16x8 bf = *(const bf16x8*)(xT + (size_t)(nt * 16 + l15) * N_BC + k + koff);
            acc[nt] = __builtin_amdgcn_mfma_f32_16x16x32_bf16(af, bf, acc[nt], 0, 0, 0);
        }
    }

    // ---- temporal weighting: p[r] = sum_t kern[row, t] * y[row, t] ----
    float p[4] = {0.f, 0.f, 0.f, 0.f};
    #pragma unroll
    for (int nt = 0; nt < 4; ++nt) {
        int t = nt * 16 + l15;
        if (t < T_K) {
            #pragma unroll
            for (int r = 0; r < 4; ++r) {
                int grow = a0 + quad * 4 + r;
                p[r] += acc[nt][r] * kern[grow * T_K + t];
            }
        }
    }
    #pragma unroll
    for (int m = 1; m <= 8; m <<= 1) {
        #pragma unroll
        for (int r = 0; r < 4; ++r) p[r] += __shfl_xor(p[r], m);
    }

    if (l15 == 0) {
        #pragma unroll
        for (int r = 0; r < 4; ++r)
            partials[ksub * N_AC + a0 + quad * 4 + r] = p[r];
    }
}

// ---------------------------------------------------------------------------
// Final: reduce K-split partials, fused sigmoid
// ---------------------------------------------------------------------------
__global__ void ac_final_kernel(const float* __restrict__ partials,
                                const float* __restrict__ slope,
                                const float* __restrict__ offs,
                                float* __restrict__ out) {
    int a = blockIdx.x * blockDim.x + threadIdx.x;
    if (a >= N_AC) return;
    float s = 0.f;
    #pragma unroll
    for (int ks = 0; ks < KSPLIT; ++ks) s += partials[ks * N_AC + a];
    float z = slope[a] * (s - offs[a]);
    out[a] = 1.0f / (1.0f + __expf(-z));
}

extern "C" void kernel_launch(void* const* d_in, const int* in_sizes, int n_in,
                              void* d_out, int out_size, void* d_ws, size_t ws_size,
                              hipStream_t stream) {
    const float* x     = (const float*)d_in[0];  // (N_BC, T_K)
    const float* W     = (const float*)d_in[1];  // (N_AC, N_BC)
    const float* kern  = (const float*)d_in[2];  // (N_AC, T_K)
    const float* slope = (const float*)d_in[3];  // (N_AC,)
    const float* offs  = (const float*)d_in[4];  // (N_AC,)
    float* out = (float*)d_out;

    __bf16* xT      = (__bf16*)d_ws;                                   // 1 MB
    float* partials = (float*)((char*)d_ws + (size_t)T_PAD * N_BC * sizeof(__bf16));

    xpose_kernel<<<dim3(T_PAD * N_BC / 256), dim3(256), 0, stream>>>(x, xT);
    ac_gemm_kernel<<<dim3(N_AC / 16, KSPLIT / 4), dim3(256), 0, stream>>>(
        W, xT, kern, partials);
    ac_final_kernel<<<dim3(N_AC / 256), dim3(256), 0, stream>>>(
        partials, slope, offs, out);
}